// Round 3
// baseline (359.437 us; speedup 1.0000x reference)
//
#include <hip/hip_runtime.h>

#define D 64
#define K 512
#define NVEC 131072   // 8192 * 16
#define BLOCK 256
#define CHUNK 64                // codes staged per LDS chunk (16 KB)
#define NCHUNK (K / CHUNK)      // 8

// Kernel A: w2half[k] = 0.5 * |w_k|^2 ; also zero the loss slot.
__global__ __launch_bounds__(64) void vq_prep(const float* __restrict__ w,
                                              float* __restrict__ w2half,
                                              float* __restrict__ loss_slot) {
    int k = blockIdx.x * 64 + threadIdx.x;
    if (blockIdx.x == 0 && threadIdx.x == 0) loss_slot[0] = 0.0f;
    if (k < K) {
        const float4* wv = (const float4*)(w + k * D);
        float s0 = 0.f, s1 = 0.f, s2 = 0.f, s3 = 0.f;
#pragma unroll
        for (int i = 0; i < D / 4; ++i) {
            float4 t = wv[i];
            s0 = fmaf(t.x, t.x, s0);
            s1 = fmaf(t.y, t.y, s1);
            s2 = fmaf(t.z, t.z, s2);
            s3 = fmaf(t.w, t.w, s3);
        }
        w2half[k] = 0.5f * ((s0 + s1) + (s2 + s3));
    }
}

// Kernel B: one thread per z-vector. score(k) = 0.5|w_k|^2 - z.w_k.
// Codebook staged chunk-by-chunk into LDS (cooperative, coalesced), then read
// with wave-uniform addresses -> broadcast ds_read_b128 feeding v_fma v,v.
// Arithmetic order identical to the round-2 kernel (absmax was 0.0).
__global__ __launch_bounds__(BLOCK) void vq_main(const float* __restrict__ z_all,
                                                 const float* __restrict__ w,
                                                 const float* __restrict__ w2half,
                                                 float* __restrict__ out,
                                                 float* __restrict__ loss_slot) {
    __shared__ float rows[CHUNK * D];   // 16 KB: current chunk of codebook rows
    __shared__ float w2s[K];            // 2 KB: all 0.5*|w|^2

    const int t = threadIdx.x;
    const int v = blockIdx.x * BLOCK + t;

    for (int i = t; i < K; i += BLOCK) w2s[i] = w2half[i];

    // Load z (negated so the inner loop is a pure fma: acc += (-z)*w).
    const float4* zv = (const float4*)(z_all + (size_t)v * D);
    float zn[D];
#pragma unroll
    for (int i = 0; i < D / 4; ++i) {
        float4 tt = zv[i];
        zn[4 * i + 0] = -tt.x;
        zn[4 * i + 1] = -tt.y;
        zn[4 * i + 2] = -tt.z;
        zn[4 * i + 3] = -tt.w;
    }

    float best = 3.402823466e+38f;
    int bidx = 0;

    for (int c = 0; c < NCHUNK; ++c) {
        // Prefetch this chunk into registers (issues while other waves may
        // still be finishing the previous chunk's compute).
        const float4* src = (const float4*)(w + c * CHUNK * D);
        float4 r0 = src[0 * BLOCK + t];
        float4 r1 = src[1 * BLOCK + t];
        float4 r2 = src[2 * BLOCK + t];
        float4 r3 = src[3 * BLOCK + t];
        __syncthreads();                 // WAR: previous chunk fully consumed
        float4* dst = (float4*)rows;
        dst[0 * BLOCK + t] = r0;
        dst[1 * BLOCK + t] = r1;
        dst[2 * BLOCK + t] = r2;
        dst[3 * BLOCK + t] = r3;
        __syncthreads();                 // RAW: chunk visible to all waves

        const int kbase = c * CHUNK;
#pragma unroll 2
        for (int kk = 0; kk < CHUNK; ++kk) {
            const float4* row = (const float4*)(rows + kk * D);  // wave-uniform
            float a0 = w2s[kbase + kk], a1 = 0.f, a2 = 0.f, a3 = 0.f;
#pragma unroll
            for (int dd = 0; dd < D / 4; ++dd) {
                float4 rv = row[dd];
                a0 = fmaf(zn[4 * dd + 0], rv.x, a0);
                a1 = fmaf(zn[4 * dd + 1], rv.y, a1);
                a2 = fmaf(zn[4 * dd + 2], rv.z, a2);
                a3 = fmaf(zn[4 * dd + 3], rv.w, a3);
            }
            float s = (a0 + a1) + (a2 + a3);
            int kidx = kbase + kk;
            bool lt = s < best;          // strict < keeps first index (jnp.argmin)
            best = lt ? s : best;
            bidx = lt ? kidx : bidx;
        }
    }

    // Output: out = z + (q - z) (reference STE rounding); elementwise loss.
    const float4* qv = (const float4*)(w + bidx * D);
    float4* ov = (float4*)(out + (size_t)v * D);
    float lsum = 0.f;
#pragma unroll
    for (int i = 0; i < D / 4; ++i) {
        float4 q = qv[i];
        float z0 = -zn[4 * i + 0], z1 = -zn[4 * i + 1];
        float z2 = -zn[4 * i + 2], z3 = -zn[4 * i + 3];
        float t0 = q.x - z0, t1 = q.y - z1, t2 = q.z - z2, t3 = q.w - z3;
        float4 o;
        o.x = z0 + t0;
        o.y = z1 + t1;
        o.z = z2 + t2;
        o.w = z3 + t3;
        ov[i] = o;
        lsum = fmaf(t0, t0, lsum);
        lsum = fmaf(t1, t1, lsum);
        lsum = fmaf(t2, t2, lsum);
        lsum = fmaf(t3, t3, lsum);
    }

    // Block reduction of the loss partial sums.
#pragma unroll
    for (int off = 32; off > 0; off >>= 1) lsum += __shfl_down(lsum, off, 64);
    __shared__ float red[BLOCK / 64];
    const int lane = threadIdx.x & 63;
    const int wid = threadIdx.x >> 6;
    if (lane == 0) red[wid] = lsum;
    __syncthreads();
    if (threadIdx.x == 0) {
        float s = 0.f;
#pragma unroll
        for (int i = 0; i < BLOCK / 64; ++i) s += red[i];
        // vq_loss = 1.25 * sum / (8192*16*64); 1.25/2^23 is exact in fp32.
        atomicAdd(loss_slot, s * (1.25f / 8388608.0f));
    }
}

extern "C" void kernel_launch(void* const* d_in, const int* in_sizes, int n_in,
                              void* d_out, int out_size, void* d_ws, size_t ws_size,
                              hipStream_t stream) {
    const float* latents = (const float*)d_in[0];   // [8192, 1024] f32
    const float* weight  = (const float*)d_in[1];   // [512, 64] f32
    float* out = (float*)d_out;                     // 8388608 outputs + 1 loss
    float* loss_slot = out + (size_t)NVEC * D;
    float* w2half = (float*)d_ws;                   // 512 floats of scratch

    vq_prep<<<8, 64, 0, stream>>>(weight, w2half, loss_slot);
    vq_main<<<NVEC / BLOCK, BLOCK, 0, stream>>>(latents, weight, w2half, out, loss_slot);
}